// Round 9
// baseline (381.178 us; speedup 1.0000x reference)
//
#include <hip/hip_runtime.h>
#include <hip/hip_bf16.h>

typedef __hip_bfloat16 bf16;
typedef __attribute__((ext_vector_type(8))) short bf16x8;
typedef __attribute__((ext_vector_type(4))) float f32x4;

#define NEG_SLOPE 0.01f
#define FGW 0.1f

__device__ __forceinline__ float b2f(bf16 v) { return __bfloat162float(v); }

// flagged boundary load: isbf=1 -> data is bf16, else f32
__device__ __forceinline__ float ldf(const void* p, size_t i, int isbf) {
    return isbf ? b2f(((const bf16*)p)[i]) : ((const float*)p)[i];
}

// bf16 bits (ushort) <-> float
__device__ __forceinline__ float bu2f(unsigned short u) {
    return __uint_as_float(((unsigned)u) << 16);
}
__device__ __forceinline__ unsigned short f2bu(float f) {
    return __bfloat16_as_ushort(__float2bfloat16(f));  // RNE
}

__device__ __forceinline__ float waveReduceSum(float v) {
#pragma unroll
    for (int o = 32; o > 0; o >>= 1) v += __shfl_down(v, o, 64);
    return v;
}

#define ATOMIC_ADD_F32(p, v) unsafeAtomicAdd((p), (v))

// ---------------- degree histogram + dtype detect + sscal zero + weight packing ----------------
__global__ __launch_bounds__(256) void k_degdet(const int* __restrict__ ei, int* __restrict__ deg, int E,
                                                const unsigned short* __restrict__ xr,
                                                float* __restrict__ sscal, int* __restrict__ flag,
                                                const void* __restrict__ W1, const void* __restrict__ W2,
                                                unsigned short* __restrict__ Wp1h,
                                                unsigned short* __restrict__ Wp1l,
                                                unsigned short* __restrict__ Wp2) {
    __shared__ int sflag;
    const int t = threadIdx.x;
    const bool packer = (blockIdx.x < 128);
    if (packer) {
        if (t < 64) {
            int big = 0;
            for (int i = t; i < 256; i += 64) {
                int ex = (xr[i] >> 7) & 0xFF;
                if (ex >= 0xBF) big = 1;   // |bf16| >= 2^64 impossible for N(0,1) data
            }
            unsigned long long mk = __ballot(big);
            if (t == 0) sflag = (mk == 0ull) ? 1 : 0;
        }
        __syncthreads();
        const int isbf = sflag;
        if (blockIdx.x == 0 && t == 0) {
            *flag = isbf;
            sscal[0] = 0.f; sscal[1] = 0.f;
        }
        int id = blockIdx.x * 256 + t;       // [0, 32768)
        {   // W1: 16 tiles x 4 ko x 64 lanes x 8 j   (128x256), hi/lo split
            int j = id & 7, l = (id >> 3) & 63, ko = (id >> 9) & 3, T = id >> 11;
            int k = ko * 32 + (l >> 4) * 8 + j, col = T * 16 + (l & 15);
            float wv = ldf(W1, (size_t)k * 256 + col, isbf);
            unsigned short hi = f2bu(wv);
            Wp1h[id] = hi;
            Wp1l[id] = f2bu(wv - bu2f(hi));  // exactly 0 for bf16 inputs
        }
        if (id < 16384) {  // W2: 4 tiles x 8 ko x 64 lanes x 8 j    (256x64)
            int j = id & 7, l = (id >> 3) & 63, ko = (id >> 9) & 7, T = id >> 12;
            int k = ko * 32 + (l >> 4) * 8 + j, col = T * 16 + (l & 15);
            Wp2[id] = f2bu(ldf(W2, (size_t)k * 64 + col, isbf));
        }
    }
    int e = blockIdx.x * 256 + t;
    if (e < E) atomicAdd(&deg[ei[E + e]], 1);
}

// ---------------- parallel scan, phase A: per-chunk inclusive scan of PADDED degrees ----------------
__global__ __launch_bounds__(256) void k_scanA(const int* __restrict__ deg, int* __restrict__ tmp,
                                               int* __restrict__ bsum, int N) {
    __shared__ int part[256];
    const int t = threadIdx.x;
    int i = blockIdx.x * 256 + t;
    int v = (i < N) ? ((deg[i] + 3) & ~3) : 0;   // pad each dst's slot count to x4
    part[t] = v;
    __syncthreads();
    for (int o = 1; o < 256; o <<= 1) {
        int add = (t >= o) ? part[t - o] : 0;
        __syncthreads();
        part[t] += add;
        __syncthreads();
    }
    if (i < N) tmp[i] = part[t];          // inclusive within chunk
    if (t == 255) bsum[blockIdx.x] = part[255];
}

// ---------------- phase B: exclusive-scan the block sums (1 block) ----------------
__global__ __launch_bounds__(256) void k_scanB(int* __restrict__ bsum, int nb, int* __restrict__ rowptrN) {
    __shared__ int part[256];
    const int t = threadIdx.x;
    const int K = (nb + 255) / 256;       // <= 8 for N <= 524288
    int vs[8];
    int lsum = 0;
#pragma unroll
    for (int k = 0; k < 8; k++) {
        int idx = t * K + k;
        vs[k] = (k < K && idx < nb) ? bsum[idx] : 0;
        lsum += vs[k];
    }
    part[t] = lsum;
    __syncthreads();
    for (int o = 1; o < 256; o <<= 1) {
        int add = (t >= o) ? part[t - o] : 0;
        __syncthreads();
        part[t] += add;
        __syncthreads();
    }
    int excl = part[t] - lsum;
#pragma unroll
    for (int k = 0; k < 8; k++) {
        int idx = t * K + k;
        if (k < K && idx < nb) { bsum[idx] = excl; excl += vs[k]; }
    }
    if (t == 255) *rowptrN = part[255];   // total = padded E
}

// ---------------- phase C: rowptr = base + local-exclusive ; zero cursor ; fill pad slots ----------------
__global__ __launch_bounds__(256) void k_scanC(const int* __restrict__ deg, const int* __restrict__ tmp,
                                               const int* __restrict__ bsum, int* __restrict__ rowptr,
                                               int* __restrict__ cursor, int* __restrict__ csr_src, int N) {
    int i = blockIdx.x * 256 + threadIdx.x;
    if (i >= N) return;
    int dg = deg[i];
    int pd = (dg + 3) & ~3;
    int base = bsum[blockIdx.x] + tmp[i] - pd;
    rowptr[i] = base;
    cursor[i] = 0;
    for (int j = dg; j < pd; j++) csr_src[base + j] = N;   // fake src id N -> e = 0
}

__global__ __launch_bounds__(256) void k_scatter(const int* __restrict__ ei, const int* __restrict__ rowptr,
                                                 int* __restrict__ cursor, int* __restrict__ csr_src, int E) {
    int e = blockIdx.x * 256 + threadIdx.x;
    if (e >= E) return;
    int d = ei[E + e];
    int pos = atomicAdd(&cursor[d], 1);
    csr_src[rowptr[d] + pos] = ei[e];
}

// ---------------- GEMM1 (64 rows/block, split-bf16 MFMA): h1(bf16) = x@W1 ; stats ; rwsum ----------------
// h1 = x_hi*W_hi + x_lo*W_hi + x_hi*W_lo  (fp32 accum) -> products accurate to ~2e-6 rel.
// bf16 input: staging is a RAW uint4 copy (f2bu(bu2f(u)) == u) -> no cvt round-trip; single-MFMA path.
// Block 0 also initializes the fake src row N (h1[N]=0, pk1[N]={-1e30 x4, 0, 0,..}).
__global__ __launch_bounds__(256) void k_gemm1f(const void* __restrict__ x,
                                                const unsigned short* __restrict__ Wp1h,
                                                const unsigned short* __restrict__ Wp1l,
                                                const void* __restrict__ attl,
                                                const void* __restrict__ attr,
                                                unsigned short* __restrict__ h1,
                                                float* __restrict__ pk1,     // [N+1][8]
                                                float* __restrict__ al1,
                                                float* __restrict__ rwS,
                                                int N, const int* __restrict__ flag) {
    const int isbf = *flag;
    __shared__ unsigned short Ash[64 * 136];   // 17.4 KB hi tile
    __shared__ unsigned short Asl[64 * 136];   // 17.4 KB lo tile
    __shared__ float rpart[64];
    const int row0 = blockIdx.x * 64;
    const int t = threadIdx.x;
    const int w = t >> 6, lane = t & 63;
    const int m = lane & 15, quad = lane >> 4;

    if (blockIdx.x == 0) {   // fake row N init (row N untouched by the GEMM below)
        if (t < 32) *reinterpret_cast<uint4*>(&h1[(size_t)N * 256 + t * 8]) = (uint4){0u, 0u, 0u, 0u};
        if (t < 8) pk1[(size_t)N * 8 + t] = (t < 4) ? -1e30f : 0.f;
    }

    // stage x tile as hi/lo bf16 pair (lo == 0 when input is bf16 -> raw copy, no Asl)
#pragma unroll
    for (int it = 0; it < 4; it++) {
        int idx = it * 256 + t;
        int r = idx >> 4, c = idx & 15;
        if (isbf) {
            uint4 raw = {0u, 0u, 0u, 0u};
            if (row0 + r < N) {
                const unsigned short* xu = (const unsigned short*)x;
                raw = *reinterpret_cast<const uint4*>(xu + (size_t)(row0 + r) * 128 + c * 8);
            }
            *reinterpret_cast<uint4*>(&Ash[r * 136 + c * 8]) = raw;
        } else {
            float v[8];
            if (row0 + r < N) {
                const float* xf = (const float*)x;
                float4 a = *reinterpret_cast<const float4*>(xf + (size_t)(row0 + r) * 128 + c * 8);
                float4 b = *reinterpret_cast<const float4*>(xf + (size_t)(row0 + r) * 128 + c * 8 + 4);
                v[0] = a.x; v[1] = a.y; v[2] = a.z; v[3] = a.w;
                v[4] = b.x; v[5] = b.y; v[6] = b.z; v[7] = b.w;
            } else {
#pragma unroll
                for (int k = 0; k < 8; k++) v[k] = 0.f;
            }
            unsigned short hi[8], lo[8];
#pragma unroll
            for (int k = 0; k < 8; k++) {
                hi[k] = f2bu(v[k]);
                lo[k] = f2bu(v[k] - bu2f(hi[k]));
            }
            *reinterpret_cast<uint4*>(&Ash[r * 136 + c * 8]) = *reinterpret_cast<const uint4*>(hi);
            *reinterpret_cast<uint4*>(&Asl[r * 136 + c * 8]) = *reinterpret_cast<const uint4*>(lo);
        }
    }
    __syncthreads();

    // wave w owns head w = col-tiles w*4..w*4+3; hoist B_hi frags, stream B_lo in-loop
    bf16x8 Bh[4][4];
#pragma unroll
    for (int tt = 0; tt < 4; tt++)
#pragma unroll
        for (int ko = 0; ko < 4; ko++)
            Bh[tt][ko] = *reinterpret_cast<const bf16x8*>(
                &Wp1h[(size_t)(((w * 4 + tt) * 4 + ko) * 64 + lane) * 8]);
    float avl[4], avr[4];
#pragma unroll
    for (int tt = 0; tt < 4; tt++) {
        int col = (w * 4 + tt) * 16 + m;
        avl[tt] = ldf(attl, col, isbf);
        avr[tt] = ldf(attr, col, isbf);
    }
    for (int sub = 0; sub < 4; sub++) {
        const int rbase = sub * 16;
        bf16x8 Ah[4];
#pragma unroll
        for (int ko = 0; ko < 4; ko++)
            Ah[ko] = *reinterpret_cast<const bf16x8*>(&Ash[(rbase + m) * 136 + ko * 32 + quad * 8]);
        f32x4 Cf[4];
#pragma unroll
        for (int tt = 0; tt < 4; tt++) Cf[tt] = (f32x4){0.f, 0.f, 0.f, 0.f};
        if (isbf) {
#pragma unroll
            for (int ko = 0; ko < 4; ko++)
#pragma unroll
                for (int tt = 0; tt < 4; tt++)
                    Cf[tt] = __builtin_amdgcn_mfma_f32_16x16x32_bf16(Ah[ko], Bh[tt][ko], Cf[tt], 0, 0, 0);
        } else {
            bf16x8 Al[4];
#pragma unroll
            for (int ko = 0; ko < 4; ko++)
                Al[ko] = *reinterpret_cast<const bf16x8*>(&Asl[(rbase + m) * 136 + ko * 32 + quad * 8]);
#pragma unroll
            for (int ko = 0; ko < 4; ko++)
#pragma unroll
                for (int tt = 0; tt < 4; tt++) {   // 4 independent chains per ko step
                    Cf[tt] = __builtin_amdgcn_mfma_f32_16x16x32_bf16(Ah[ko], Bh[tt][ko], Cf[tt], 0, 0, 0);
                    Cf[tt] = __builtin_amdgcn_mfma_f32_16x16x32_bf16(Al[ko], Bh[tt][ko], Cf[tt], 0, 0, 0);
                    bf16x8 Bl = *reinterpret_cast<const bf16x8*>(
                        &Wp1l[(size_t)(((w * 4 + tt) * 4 + ko) * 64 + lane) * 8]);
                    Cf[tt] = __builtin_amdgcn_mfma_f32_16x16x32_bf16(Ah[ko], Bl, Cf[tt], 0, 0, 0);
                }
        }
        // stores + fp32 sidecar (col 255, ~fp32-accurate)
#pragma unroll
        for (int tt = 0; tt < 4; tt++) {
            int col = (w * 4 + tt) * 16 + m;
#pragma unroll
            for (int reg = 0; reg < 4; reg++) {
                int row = row0 + rbase + quad * 4 + reg;
                if (row < N) h1[(size_t)row * 256 + col] = f2bu(Cf[tt][reg]);
            }
        }
        if (w == 3 && m == 15) {
#pragma unroll
            for (int reg = 0; reg < 4; reg++) {
                int row = row0 + rbase + quad * 4 + reg;
                if (row < N) pk1[(size_t)row * 8 + 5] = Cf[3][reg];   // col 255
            }
        }
        // stats for head w
        float sl[4], sr[4];
#pragma unroll
        for (int reg = 0; reg < 4; reg++) {
            float a = 0.f, b = 0.f;
#pragma unroll
            for (int tt = 0; tt < 4; tt++) {
                a = fmaf(avl[tt], Cf[tt][reg], a);
                b = fmaf(avr[tt], Cf[tt][reg], b);
            }
            sl[reg] = a; sr[reg] = b;
        }
#pragma unroll
        for (int off = 8; off >= 1; off >>= 1) {
#pragma unroll
            for (int reg = 0; reg < 4; reg++) {
                sl[reg] += __shfl_down(sl[reg], off, 64);
                sr[reg] += __shfl_down(sr[reg], off, 64);
            }
        }
        if (m == 0) {
#pragma unroll
            for (int reg = 0; reg < 4; reg++) {
                int row = row0 + rbase + quad * 4 + reg;
                if (row < N) {
                    al1[(size_t)row * 4 + w] = sl[reg];
                    pk1[(size_t)row * 8 + w] = sr[reg];
                }
            }
        }
    }
    // reward weights: EXACT input col 127 from global (f32 when f32)
    if (t < 64) {
        int row = row0 + t;
        float rr = 0.f;
        if (row < N) {
            float a = fabsf(ldf(x, (size_t)row * 128 + 127, isbf));
            rr = 1.f / (a + 1e-6f);
            pk1[(size_t)row * 8 + 4] = logf(rr);
        }
        rpart[t] = rr;
    }
    __syncthreads();
    if (t == 0) {
        float s = 0.f;
#pragma unroll
        for (int i = 0; i < 64; i++) s += rpart[i];
        ATOMIC_ADD_F32(rwS, s);
    }
}

// ---------------- FUSED layer1 aggregation + GEMM2: x2 never leaves the block ----------------
// 16 waves/block, one dst per wave (proven non-serialized mapping). Phase 1 = agg1's depth-3
// gather pipeline (padded CSR, mask-free, indices pre-resolved per chunk); x2 row lands in LDS
// X[16][264] as bf16 + fp32 col-255 sidecar xc[16]. Phase 2 = gemm2's 16x64 MFMA tile (K=256)
// by waves 0..3 from LDS: h2(bf16) + al2/pk2 stats + rwsum2. Saves the 51MB x2b round-trip and
// removes agg1's 25MB write stream from the gather-critical kernel. h2 lives in the dead x2b
// region (h1 stays intact for concurrent gathers by other blocks).
__global__ __launch_bounds__(1024) void k_aggm(const int* __restrict__ rowptr,
                                               const int* __restrict__ csr_src,
                                               const float* __restrict__ al1,
                                               const float* __restrict__ pk1,
                                               const float* __restrict__ rwS,
                                               const unsigned short* __restrict__ h1,
                                               const unsigned short* __restrict__ Wp2,
                                               const void* __restrict__ attl,
                                               const void* __restrict__ attr,
                                               unsigned short* __restrict__ h2,
                                               float* __restrict__ pk2,     // [N+1][2]
                                               float* __restrict__ al2,
                                               float* __restrict__ rwS2,
                                               int N, const int* __restrict__ flag) {
    const int isbf = *flag;
    __shared__ unsigned short X[16 * 264];   // 8.3 KB x2 tile (264 stride = gemm2's layout)
    __shared__ float xc[16];                 // fp32 post-ELU col 255
    __shared__ float pl[64], pr[64], rpart[16];
    const int t = threadIdx.x;
    const int wv = t >> 6;        // 0..15: wave = dst row
    const int lane = t & 63;
    const int D0 = blockIdx.x * 16;

    if (blockIdx.x == 0) {   // layer-2 fake src row init (h2 region is fresh)
        if (t < 8) *reinterpret_cast<uint4*>(&h2[(size_t)N * 64 + t * 8]) = (uint4){0u, 0u, 0u, 0u};
        if (t == 0) { pk2[(size_t)N * 2] = -1e30f; pk2[(size_t)N * 2 + 1] = 0.f; }
    }

    // ================= phase 1: aggregation (one dst per wave) =================
    const int d = D0 + wv;
    const int q = lane & 15;          // column block
    const int g = lane >> 4;          // edge group
    const int h = q >> 2;             // head of this column block
    const bool last15 = (q == 15);
    const float gl = FGW * logf(fmaxf(*rwS, 1e-12f));
    const unsigned qo = (unsigned)q * 32u;
    const unsigned ho4 = (unsigned)h * 4u;
    const char* pk1c = (const char*)pk1;
    const char* h1c  = (const char*)h1;

    if (d < N) {
        const float al_h = al1[(size_t)d * 4 + h];
        const int beg = rowptr[d], end = rowptr[d + 1];

        float acc[16];
#pragma unroll
        for (int k = 0; k < 16; k++) acc[k] = 0.f;
        float ssum = 0.f;

        for (int base = beg; base < end; base += 32) {
            const int nst = min(end - base, 32) >> 2;   // 1..8, exact (padded)

            int sj[8];
#pragma unroll
            for (int k = 0; k < 8; k++)
                if (k < nst) sj[k] = csr_src[base + k * 4 + g];

            float arP[4]; float2 lcP[4]; uint4 h0P[4], h1P[4];

#define LD1(K) do {                                                                   \
        int s_ = sj[(K)];                                                             \
        unsigned po_ = (unsigned)s_ * 32u;                                            \
        arP[(K) & 3] = *reinterpret_cast<const float*>(pk1c + po_ + ho4);             \
        lcP[(K) & 3] = *reinterpret_cast<const float2*>(pk1c + po_ + 16u);            \
        unsigned ho_ = (unsigned)s_ * 512u + qo;                                      \
        h0P[(K) & 3] = *reinterpret_cast<const uint4*>(h1c + ho_);                    \
        h1P[(K) & 3] = *reinterpret_cast<const uint4*>(h1c + ho_ + 16u);              \
    } while (0)

#define CONS1(K) do {                                                                 \
        float a_ = al_h + arP[(K) & 3];                                               \
        a_ = fmaxf(a_, NEG_SLOPE * a_);                                               \
        a_ = fmaf(FGW, lcP[(K) & 3].x, a_ - gl);                                      \
        float e_ = __expf(a_);                                                        \
        ssum += e_;                                                                   \
        uint4 cb0_ = h0P[(K) & 3], cb1_ = h1P[(K) & 3];                               \
        unsigned uu_; float lo_, hi_;                                                 \
        uu_ = cb0_.x; lo_ = __uint_as_float(uu_ << 16); hi_ = __uint_as_float(uu_ & 0xFFFF0000u); \
        acc[0] = fmaf(e_, lo_, acc[0]);  acc[1] = fmaf(e_, hi_, acc[1]);              \
        uu_ = cb0_.y; lo_ = __uint_as_float(uu_ << 16); hi_ = __uint_as_float(uu_ & 0xFFFF0000u); \
        acc[2] = fmaf(e_, lo_, acc[2]);  acc[3] = fmaf(e_, hi_, acc[3]);              \
        uu_ = cb0_.z; lo_ = __uint_as_float(uu_ << 16); hi_ = __uint_as_float(uu_ & 0xFFFF0000u); \
        acc[4] = fmaf(e_, lo_, acc[4]);  acc[5] = fmaf(e_, hi_, acc[5]);              \
        uu_ = cb0_.w; lo_ = __uint_as_float(uu_ << 16); hi_ = __uint_as_float(uu_ & 0xFFFF0000u); \
        acc[6] = fmaf(e_, lo_, acc[6]);  acc[7] = fmaf(e_, hi_, acc[7]);              \
        uu_ = cb1_.x; lo_ = __uint_as_float(uu_ << 16); hi_ = __uint_as_float(uu_ & 0xFFFF0000u); \
        acc[8] = fmaf(e_, lo_, acc[8]);  acc[9] = fmaf(e_, hi_, acc[9]);              \
        uu_ = cb1_.y; lo_ = __uint_as_float(uu_ << 16); hi_ = __uint_as_float(uu_ & 0xFFFF0000u); \
        acc[10] = fmaf(e_, lo_, acc[10]); acc[11] = fmaf(e_, hi_, acc[11]);           \
        uu_ = cb1_.z; lo_ = __uint_as_float(uu_ << 16); hi_ = __uint_as_float(uu_ & 0xFFFF0000u); \
        acc[12] = fmaf(e_, lo_, acc[12]); acc[13] = fmaf(e_, hi_, acc[13]);           \
        uu_ = cb1_.w; lo_ = __uint_as_float(uu_ << 16); hi_ = __uint_as_float(uu_ & 0xFFFF0000u); \
        hi_ = last15 ? lcP[(K) & 3].y : hi_;   /* exact fp32 for log-sensitive col 255 */ \
        acc[14] = fmaf(e_, lo_, acc[14]); acc[15] = fmaf(e_, hi_, acc[15]);           \
    } while (0)

            LD1(0);
            if (1 < nst) LD1(1);
            if (2 < nst) LD1(2);
#pragma unroll
            for (int k = 0; k < 8; k++) {
                if (k >= nst) break;
                if (k + 3 < 8) { if (k + 3 < nst) LD1(k + 3); }
                CONS1(k);
            }
#undef LD1
#undef CONS1
        }

        // merge the 4 edge-group partials (lanes with equal q)
#pragma unroll
        for (int k = 0; k < 16; k++) {
            acc[k] += __shfl_xor(acc[k], 16, 64);
            acc[k] += __shfl_xor(acc[k], 32, 64);
        }
        ssum += __shfl_xor(ssum, 16, 64);
        ssum += __shfl_xor(ssum, 32, 64);

        const float inv = 1.f / (ssum + 1e-16f);
        // lane (g,q) finalizes cols q*16 + g*4 .. +3  (constant-indexed selects; no scratch)
        float o0 = (g == 0 ? acc[0] : g == 1 ? acc[4]  : g == 2 ? acc[8]  : acc[12]);
        float o1 = (g == 0 ? acc[1] : g == 1 ? acc[5]  : g == 2 ? acc[9]  : acc[13]);
        float o2 = (g == 0 ? acc[2] : g == 1 ? acc[6]  : g == 2 ? acc[10] : acc[14]);
        float o3 = (g == 0 ? acc[3] : g == 1 ? acc[7]  : g == 2 ? acc[11] : acc[15]);
        o0 *= inv; o1 *= inv; o2 *= inv; o3 *= inv;
        o0 = (o0 > 0.f) ? o0 : expm1f(o0);
        o1 = (o1 > 0.f) ? o1 : expm1f(o1);
        o2 = (o2 > 0.f) ? o2 : expm1f(o2);
        o3 = (o3 > 0.f) ? o3 : expm1f(o3);
        uint2 ob;
        ob.x = (unsigned)f2bu(o0) | ((unsigned)f2bu(o1) << 16);
        ob.y = (unsigned)f2bu(o2) | ((unsigned)f2bu(o3) << 16);
        *reinterpret_cast<uint2*>(&X[wv * 264 + q * 16 + g * 4]) = ob;
        if (lane == 63) xc[wv] = o3;   // fp32 post-ELU col 255
    }
    __syncthreads();

    // ================= phase 2: h2[16x64] = X @ W2 (waves 0..3, col-tile each) =================
    const int m = lane & 15, quad = lane >> 4;
    if (wv < 4) {
        f32x4 Cf = (f32x4){0.f, 0.f, 0.f, 0.f};
#pragma unroll
        for (int ko = 0; ko < 8; ko++) {
            bf16x8 Bf = *reinterpret_cast<const bf16x8*>(&Wp2[(size_t)((wv * 8 + ko) * 64 + lane) * 8]);
            bf16x8 Af = *reinterpret_cast<const bf16x8*>(&X[m * 264 + ko * 32 + quad * 8]);
            Cf = __builtin_amdgcn_mfma_f32_16x16x32_bf16(Af, Bf, Cf, 0, 0, 0);
        }
        const int col = wv * 16 + m;
        const float avl = ldf(attl, col, isbf);
        const float avr = ldf(attr, col, isbf);
        float sl[4], sr[4];
#pragma unroll
        for (int reg = 0; reg < 4; reg++) {
            int row = D0 + quad * 4 + reg;
            if (row < N) h2[(size_t)row * 64 + col] = f2bu(Cf[reg]);
            sl[reg] = avl * Cf[reg];
            sr[reg] = avr * Cf[reg];
        }
#pragma unroll
        for (int off = 8; off >= 1; off >>= 1) {
#pragma unroll
            for (int reg = 0; reg < 4; reg++) {
                sl[reg] += __shfl_down(sl[reg], off, 64);
                sr[reg] += __shfl_down(sr[reg], off, 64);
            }
        }
        if (m == 0) {
#pragma unroll
            for (int reg = 0; reg < 4; reg++) {
                pl[wv * 16 + quad * 4 + reg] = sl[reg];
                pr[wv * 16 + quad * 4 + reg] = sr[reg];
            }
        }
    }
    __syncthreads();
    if (t < 16) {
        int row = D0 + t;
        float rr = 0.f;
        if (row < N) {
            al2[row] = pl[t] + pl[16 + t] + pl[32 + t] + pl[48 + t];
            pk2[(size_t)row * 2] = pr[t] + pr[16 + t] + pr[32 + t] + pr[48 + t];
            float a = fabsf(xc[t]);   // fp32 sidecar: exact post-ELU col 255
            rr = 1.f / (a + 1e-6f);
            pk2[(size_t)row * 2 + 1] = logf(rr);
        }
        rpart[t] = rr;
    }
    __syncthreads();
    if (t == 0) {
        float s = 0.f;
#pragma unroll
        for (int i = 0; i < 16; i++) s += rpart[i];
        ATOMIC_ADD_F32(rwS2, s);
    }
}

// ---------------- layer2 aggregation + ELU + FC -> y (one dst/wave, padded CSR, depth-3) ----------------
__global__ __launch_bounds__(256) void k_agg2(const int* __restrict__ rowptr,
                                              const int* __restrict__ csr_src,
                                              const float* __restrict__ al2,
                                              const float* __restrict__ pk2,
                                              const float* __restrict__ rwS2,
                                              const unsigned short* __restrict__ h2,
                                              const void* __restrict__ fcw,
                                              const void* __restrict__ fcb,
                                              void* __restrict__ y, int N,
                                              const int* __restrict__ flag) {
    const int isbf = *flag;
    const int d = blockIdx.x * 4 + (threadIdx.x >> 6);
    if (d >= N) return;
    const int lane = threadIdx.x & 63;
    const int q = lane & 15;
    const int g = lane >> 4;
    const float gl2 = FGW * logf(fmaxf(*rwS2, 1e-12f));
    const char* pk2c = (const char*)pk2;
    const char* h2c  = (const char*)h2;
    const unsigned qo8 = (unsigned)q * 8u;

    const float al_d = al2[d];
    const int beg = rowptr[d], end = rowptr[d + 1];

    float acc[4];
#pragma unroll
    for (int k = 0; k < 4; k++) acc[k] = 0.f;
    float ssum = 0.f;

    for (int base = beg; base < end; base += 32) {
        const int nst = min(end - base, 32) >> 2;

        int sj[8];
#pragma unroll
        for (int k = 0; k < 8; k++)
            if (k < nst) sj[k] = csr_src[base + k * 4 + g];

        float2 pvP[4]; uint2 hbP[4];

#define LD2(K) do {                                                                    \
        int s_ = sj[(K)];                                                              \
        pvP[(K) & 3] = *reinterpret_cast<const float2*>(pk2c + (unsigned)s_ * 8u);     \
        hbP[(K) & 3] = *reinterpret_cast<const uint2*>(h2c + (unsigned)s_ * 128u + qo8); \
    } while (0)

#define CONS2(K) do {                                                                  \
        float a_ = al_d + pvP[(K) & 3].x;                                              \
        a_ = fmaxf(a_, NEG_SLOPE * a_);                                                \
        a_ = fmaf(FGW, pvP[(K) & 3].y, a_ - gl2);                                      \
        float e_ = __expf(a_);                                                         \
        ssum += e_;                                                                    \
        unsigned uu_ = hbP[(K) & 3].x;                                                 \
        acc[0] = fmaf(e_, __uint_as_float(uu_ << 16), acc[0]);                         \
        acc[1] = fmaf(e_, __uint_as_float(uu_ & 0xFFFF0000u), acc[1]);                 \
        uu_ = hbP[(K) & 3].y;                                                          \
        acc[2] = fmaf(e_, __uint_as_float(uu_ << 16), acc[2]);                         \
        acc[3] = fmaf(e_, __uint_as_float(uu_ & 0xFFFF0000u), acc[3]);                 \
    } while (0)

        LD2(0);
        if (1 < nst) LD2(1);
        if (2 < nst) LD2(2);
#pragma unroll
        for (int k = 0; k < 8; k++) {
            if (k >= nst) break;
            if (k + 3 < 8) { if (k + 3 < nst) LD2(k + 3); }
            CONS2(k);
        }
#undef LD2
#undef CONS2
    }

#pragma unroll
    for (int k = 0; k < 4; k++) {
        acc[k] += __shfl_xor(acc[k], 16, 64);
        acc[k] += __shfl_xor(acc[k], 32, 64);
    }
    ssum += __shfl_xor(ssum, 16, 64);
    ssum += __shfl_xor(ssum, 32, 64);

    // lane (g,q) owns col q*4+g (bijective over 64 lanes)
    float v = (g == 0 ? acc[0] : g == 1 ? acc[1] : g == 2 ? acc[2] : acc[3]) / (ssum + 1e-16f);
    v = (v > 0.f) ? v : expm1f(v);
    float r = waveReduceSum(v * ldf(fcw, q * 4 + g, isbf));
    if (lane == 0) {
        float o = r + ldf(fcb, 0, isbf);
        if (isbf) ((bf16*)y)[d] = __float2bfloat16(o);
        else      ((float*)y)[d] = o;
    }
}

extern "C" void kernel_launch(void* const* d_in, const int* in_sizes, int n_in,
                              void* d_out, int out_size, void* d_ws, size_t ws_size,
                              hipStream_t stream) {
    const void* x     = d_in[0];
    const int*  ei    = (const int*)d_in[1];
    const void* W1    = d_in[2];
    const void* attl1 = d_in[3];
    const void* attr1 = d_in[4];
    const void* W2    = d_in[5];
    const void* attl2 = d_in[6];
    const void* attr2 = d_in[7];
    const void* fcw   = d_in[8];
    const void* fcb   = d_in[9];

    const int N = in_sizes[0] / 128;  // 50000
    const int E = in_sizes[1] / 2;    // 800000
    const int NB = (N + 255) / 256;   // scan chunks
    const int E2 = E + 4 * N;         // padded CSR capacity

    // ---- workspace layout (~62 MB) ----
    float* p = (float*)d_ws;
    unsigned short* h1 = (unsigned short*)p; p += (size_t)(N + 1) * 128;   // (N+1)*256 bf16 (+fake row)
    float* pk1    = p; p += (size_t)(N + 1) * 8;   // {ar[4], logr, h1c255, pad, pad} (+fake row)
    float* al1    = p; p += (size_t)N * 4;
    unsigned short* x2b = (unsigned short*)p; p += (size_t)N * 128;  // dead region -> reused as h2
    float* x2c    = p; p += (size_t)N;       // unused (kept for layout stability)
    float* pk2    = p; p += (size_t)(N + 1) * 2;   // {ar2, logr2} (+fake row)
    float* al2    = p; p += (size_t)N;
    int* rowptr   = (int*)p; p += (size_t)N + 1;
    int* deg      = (int*)p; p += (size_t)N;
    int* cursor   = (int*)p; p += (size_t)N;
    int* stmp     = (int*)p; p += (size_t)N;   // scan phase-A inclusive partials
    int* bsum     = (int*)p; p += (size_t)NB;  // scan block sums
    int* csr_src  = (int*)p; p += (size_t)E2;  // padded CSR
    p = (float*)(((uintptr_t)p + 15) & ~(uintptr_t)15);  // 16B align for frag loads
    unsigned short* Wp1h = (unsigned short*)p; p += 16384;  // 32768 bf16
    unsigned short* Wp1l = (unsigned short*)p; p += 16384;  // 32768 bf16
    unsigned short* Wp2  = (unsigned short*)p; p += 8192;   // 16384 bf16
    float* sscal  = p; p += 4;               // [0]=rwsum L1, [1]=rwsum L2, [2]=dtype flag
    int* dflag = (int*)(sscal + 2);
    (void)x2c;

    unsigned short* h2 = x2b;   // h2 ((N+1)*64 bf16) lives in the dead x2b region (h1 stays live)

    // deg must be zero before the histogram (ws re-poisoned each call)
    hipMemsetAsync(deg, 0, (size_t)N * 4, stream);

    // ---- CSR build + dtype detect + weight packing ----
    k_degdet<<<(E + 255) / 256, 256, 0, stream>>>(ei, deg, E, (const unsigned short*)x, sscal, dflag,
                                                  W1, W2, Wp1h, Wp1l, Wp2);
    k_scanA<<<NB, 256, 0, stream>>>(deg, stmp, bsum, N);
    k_scanB<<<1, 256, 0, stream>>>(bsum, NB, &rowptr[N]);
    k_scanC<<<NB, 256, 0, stream>>>(deg, stmp, bsum, rowptr, cursor, csr_src, N);
    k_scatter<<<(E + 255) / 256, 256, 0, stream>>>(ei, rowptr, cursor, csr_src, E);

    // ---- layer 1 (GEMM1) ----
    k_gemm1f<<<(N + 63) / 64, 256, 0, stream>>>(x, Wp1h, Wp1l, attl1, attr1, h1, pk1, al1,
                                                &sscal[0], N, dflag);

    // ---- fused: layer1 aggregation + GEMM2 ----
    k_aggm<<<(N + 15) / 16, 1024, 0, stream>>>(rowptr, csr_src, al1, pk1, &sscal[0], h1,
                                               Wp2, attl2, attr2, h2, pk2, al2,
                                               &sscal[1], N, dflag);

    // ---- layer 2 aggregation + FC ----
    k_agg2<<<(N + 3) / 4, 256, 0, stream>>>(rowptr, csr_src, al2, pk2,
                                            &sscal[1], h2, fcw, fcb, d_out, N, dflag);
}

// Round 10
// 319.406 us; speedup vs baseline: 1.1934x; 1.1934x over previous
//
#include <hip/hip_runtime.h>
#include <hip/hip_bf16.h>

typedef __hip_bfloat16 bf16;
typedef __attribute__((ext_vector_type(8))) short bf16x8;
typedef __attribute__((ext_vector_type(4))) float f32x4;

#define NEG_SLOPE 0.01f
#define FGW 0.1f

__device__ __forceinline__ float b2f(bf16 v) { return __bfloat162float(v); }

// flagged boundary load: isbf=1 -> data is bf16, else f32
__device__ __forceinline__ float ldf(const void* p, size_t i, int isbf) {
    return isbf ? b2f(((const bf16*)p)[i]) : ((const float*)p)[i];
}

// bf16 bits (ushort) <-> float
__device__ __forceinline__ float bu2f(unsigned short u) {
    return __uint_as_float(((unsigned)u) << 16);
}
__device__ __forceinline__ unsigned short f2bu(float f) {
    return __bfloat16_as_ushort(__float2bfloat16(f));  // RNE
}

__device__ __forceinline__ float waveReduceSum(float v) {
#pragma unroll
    for (int o = 32; o > 0; o >>= 1) v += __shfl_down(v, o, 64);
    return v;
}

#define ATOMIC_ADD_F32(p, v) unsafeAtomicAdd((p), (v))

// ---------------- degree histogram + dtype detect + sscal zero + weight packing ----------------
__global__ __launch_bounds__(256) void k_degdet(const int* __restrict__ ei, int* __restrict__ deg, int E,
                                                const unsigned short* __restrict__ xr,
                                                float* __restrict__ sscal, int* __restrict__ flag,
                                                const void* __restrict__ W1, const void* __restrict__ W2,
                                                unsigned short* __restrict__ Wp1h,
                                                unsigned short* __restrict__ Wp1l,
                                                unsigned short* __restrict__ Wp2) {
    __shared__ int sflag;
    const int t = threadIdx.x;
    const bool packer = (blockIdx.x < 128);
    if (packer) {
        if (t < 64) {
            int big = 0;
            for (int i = t; i < 256; i += 64) {
                int ex = (xr[i] >> 7) & 0xFF;
                if (ex >= 0xBF) big = 1;   // |bf16| >= 2^64 impossible for N(0,1) data
            }
            unsigned long long mk = __ballot(big);
            if (t == 0) sflag = (mk == 0ull) ? 1 : 0;
        }
        __syncthreads();
        const int isbf = sflag;
        if (blockIdx.x == 0 && t == 0) {
            *flag = isbf;
            sscal[0] = 0.f; sscal[1] = 0.f;
        }
        int id = blockIdx.x * 256 + t;       // [0, 32768)
        {   // W1: 16 tiles x 4 ko x 64 lanes x 8 j   (128x256), hi/lo split
            int j = id & 7, l = (id >> 3) & 63, ko = (id >> 9) & 3, T = id >> 11;
            int k = ko * 32 + (l >> 4) * 8 + j, col = T * 16 + (l & 15);
            float wv = ldf(W1, (size_t)k * 256 + col, isbf);
            unsigned short hi = f2bu(wv);
            Wp1h[id] = hi;
            Wp1l[id] = f2bu(wv - bu2f(hi));  // exactly 0 for bf16 inputs
        }
        if (id < 16384) {  // W2: 4 tiles x 8 ko x 64 lanes x 8 j    (256x64)
            int j = id & 7, l = (id >> 3) & 63, ko = (id >> 9) & 7, T = id >> 12;
            int k = ko * 32 + (l >> 4) * 8 + j, col = T * 16 + (l & 15);
            Wp2[id] = f2bu(ldf(W2, (size_t)k * 64 + col, isbf));
        }
    }
    int e = blockIdx.x * 256 + t;
    if (e < E) atomicAdd(&deg[ei[E + e]], 1);
}

// ---------------- parallel scan, phase A: per-chunk inclusive scan of PADDED degrees ----------------
__global__ __launch_bounds__(256) void k_scanA(const int* __restrict__ deg, int* __restrict__ tmp,
                                               int* __restrict__ bsum, int N) {
    __shared__ int part[256];
    const int t = threadIdx.x;
    int i = blockIdx.x * 256 + t;
    int v = (i < N) ? ((deg[i] + 3) & ~3) : 0;   // pad each dst's slot count to x4
    part[t] = v;
    __syncthreads();
    for (int o = 1; o < 256; o <<= 1) {
        int add = (t >= o) ? part[t - o] : 0;
        __syncthreads();
        part[t] += add;
        __syncthreads();
    }
    if (i < N) tmp[i] = part[t];          // inclusive within chunk
    if (t == 255) bsum[blockIdx.x] = part[255];
}

// ---------------- phase B: exclusive-scan the block sums (1 block) ----------------
__global__ __launch_bounds__(256) void k_scanB(int* __restrict__ bsum, int nb, int* __restrict__ rowptrN) {
    __shared__ int part[256];
    const int t = threadIdx.x;
    const int K = (nb + 255) / 256;       // <= 8 for N <= 524288
    int vs[8];
    int lsum = 0;
#pragma unroll
    for (int k = 0; k < 8; k++) {
        int idx = t * K + k;
        vs[k] = (k < K && idx < nb) ? bsum[idx] : 0;
        lsum += vs[k];
    }
    part[t] = lsum;
    __syncthreads();
    for (int o = 1; o < 256; o <<= 1) {
        int add = (t >= o) ? part[t - o] : 0;
        __syncthreads();
        part[t] += add;
        __syncthreads();
    }
    int excl = part[t] - lsum;
#pragma unroll
    for (int k = 0; k < 8; k++) {
        int idx = t * K + k;
        if (k < K && idx < nb) { bsum[idx] = excl; excl += vs[k]; }
    }
    if (t == 255) *rowptrN = part[255];   // total = padded E
}

// ---------------- phase C: rowptr = base + local-exclusive ; zero cursor ; fill pad slots ----------------
__global__ __launch_bounds__(256) void k_scanC(const int* __restrict__ deg, const int* __restrict__ tmp,
                                               const int* __restrict__ bsum, int* __restrict__ rowptr,
                                               int* __restrict__ cursor, int* __restrict__ csr_src, int N) {
    int i = blockIdx.x * 256 + threadIdx.x;
    if (i >= N) return;
    int dg = deg[i];
    int pd = (dg + 3) & ~3;
    int base = bsum[blockIdx.x] + tmp[i] - pd;
    rowptr[i] = base;
    cursor[i] = 0;
    for (int j = dg; j < pd; j++) csr_src[base + j] = N;   // fake src id N -> e = 0
}

__global__ __launch_bounds__(256) void k_scatter(const int* __restrict__ ei, const int* __restrict__ rowptr,
                                                 int* __restrict__ cursor, int* __restrict__ csr_src, int E) {
    int e = blockIdx.x * 256 + threadIdx.x;
    if (e >= E) return;
    int d = ei[E + e];
    int pos = atomicAdd(&cursor[d], 1);
    csr_src[rowptr[d] + pos] = ei[e];
}

// ---------------- GEMM1 (64 rows/block, split-bf16 MFMA): h1(bf16) = x@W1 ; stats ; rwsum ----------------
// h1 = x_hi*W_hi + x_lo*W_hi + x_hi*W_lo  (fp32 accum) -> products accurate to ~2e-6 rel.
// bf16 input: staging is a RAW uint4 copy (f2bu(bu2f(u)) == u) -> no cvt round-trip; single-MFMA path.
// Block 0 also initializes the fake src row N (h1[N]=0, pk1[N]={-1e30 x4, 0, 0,..}).
__global__ __launch_bounds__(256) void k_gemm1f(const void* __restrict__ x,
                                                const unsigned short* __restrict__ Wp1h,
                                                const unsigned short* __restrict__ Wp1l,
                                                const void* __restrict__ attl,
                                                const void* __restrict__ attr,
                                                unsigned short* __restrict__ h1,
                                                float* __restrict__ pk1,     // [N+1][8]
                                                float* __restrict__ al1,
                                                float* __restrict__ rwS,
                                                int N, const int* __restrict__ flag) {
    const int isbf = *flag;
    __shared__ unsigned short Ash[64 * 136];   // 17.4 KB hi tile
    __shared__ unsigned short Asl[64 * 136];   // 17.4 KB lo tile
    __shared__ float rpart[64];
    const int row0 = blockIdx.x * 64;
    const int t = threadIdx.x;
    const int w = t >> 6, lane = t & 63;
    const int m = lane & 15, quad = lane >> 4;

    if (blockIdx.x == 0) {   // fake row N init (row N untouched by the GEMM below)
        if (t < 32) *reinterpret_cast<uint4*>(&h1[(size_t)N * 256 + t * 8]) = (uint4){0u, 0u, 0u, 0u};
        if (t < 8) pk1[(size_t)N * 8 + t] = (t < 4) ? -1e30f : 0.f;
    }

    // stage x tile as hi/lo bf16 pair (lo == 0 when input is bf16 -> raw copy, no Asl)
#pragma unroll
    for (int it = 0; it < 4; it++) {
        int idx = it * 256 + t;
        int r = idx >> 4, c = idx & 15;
        if (isbf) {
            uint4 raw = {0u, 0u, 0u, 0u};
            if (row0 + r < N) {
                const unsigned short* xu = (const unsigned short*)x;
                raw = *reinterpret_cast<const uint4*>(xu + (size_t)(row0 + r) * 128 + c * 8);
            }
            *reinterpret_cast<uint4*>(&Ash[r * 136 + c * 8]) = raw;
        } else {
            float v[8];
            if (row0 + r < N) {
                const float* xf = (const float*)x;
                float4 a = *reinterpret_cast<const float4*>(xf + (size_t)(row0 + r) * 128 + c * 8);
                float4 b = *reinterpret_cast<const float4*>(xf + (size_t)(row0 + r) * 128 + c * 8 + 4);
                v[0] = a.x; v[1] = a.y; v[2] = a.z; v[3] = a.w;
                v[4] = b.x; v[5] = b.y; v[6] = b.z; v[7] = b.w;
            } else {
#pragma unroll
                for (int k = 0; k < 8; k++) v[k] = 0.f;
            }
            unsigned short hi[8], lo[8];
#pragma unroll
            for (int k = 0; k < 8; k++) {
                hi[k] = f2bu(v[k]);
                lo[k] = f2bu(v[k] - bu2f(hi[k]));
            }
            *reinterpret_cast<uint4*>(&Ash[r * 136 + c * 8]) = *reinterpret_cast<const uint4*>(hi);
            *reinterpret_cast<uint4*>(&Asl[r * 136 + c * 8]) = *reinterpret_cast<const uint4*>(lo);
        }
    }
    __syncthreads();

    // wave w owns head w = col-tiles w*4..w*4+3; hoist B_hi frags, stream B_lo in-loop
    bf16x8 Bh[4][4];
#pragma unroll
    for (int tt = 0; tt < 4; tt++)
#pragma unroll
        for (int ko = 0; ko < 4; ko++)
            Bh[tt][ko] = *reinterpret_cast<const bf16x8*>(
                &Wp1h[(size_t)(((w * 4 + tt) * 4 + ko) * 64 + lane) * 8]);
    float avl[4], avr[4];
#pragma unroll
    for (int tt = 0; tt < 4; tt++) {
        int col = (w * 4 + tt) * 16 + m;
        avl[tt] = ldf(attl, col, isbf);
        avr[tt] = ldf(attr, col, isbf);
    }
    for (int sub = 0; sub < 4; sub++) {
        const int rbase = sub * 16;
        bf16x8 Ah[4];
#pragma unroll
        for (int ko = 0; ko < 4; ko++)
            Ah[ko] = *reinterpret_cast<const bf16x8*>(&Ash[(rbase + m) * 136 + ko * 32 + quad * 8]);
        f32x4 Cf[4];
#pragma unroll
        for (int tt = 0; tt < 4; tt++) Cf[tt] = (f32x4){0.f, 0.f, 0.f, 0.f};
        if (isbf) {
#pragma unroll
            for (int ko = 0; ko < 4; ko++)
#pragma unroll
                for (int tt = 0; tt < 4; tt++)
                    Cf[tt] = __builtin_amdgcn_mfma_f32_16x16x32_bf16(Ah[ko], Bh[tt][ko], Cf[tt], 0, 0, 0);
        } else {
            bf16x8 Al[4];
#pragma unroll
            for (int ko = 0; ko < 4; ko++)
                Al[ko] = *reinterpret_cast<const bf16x8*>(&Asl[(rbase + m) * 136 + ko * 32 + quad * 8]);
#pragma unroll
            for (int ko = 0; ko < 4; ko++)
#pragma unroll
                for (int tt = 0; tt < 4; tt++) {   // 4 independent chains per ko step
                    Cf[tt] = __builtin_amdgcn_mfma_f32_16x16x32_bf16(Ah[ko], Bh[tt][ko], Cf[tt], 0, 0, 0);
                    Cf[tt] = __builtin_amdgcn_mfma_f32_16x16x32_bf16(Al[ko], Bh[tt][ko], Cf[tt], 0, 0, 0);
                    bf16x8 Bl = *reinterpret_cast<const bf16x8*>(
                        &Wp1l[(size_t)(((w * 4 + tt) * 4 + ko) * 64 + lane) * 8]);
                    Cf[tt] = __builtin_amdgcn_mfma_f32_16x16x32_bf16(Ah[ko], Bl, Cf[tt], 0, 0, 0);
                }
        }
        // stores + fp32 sidecar (col 255, ~fp32-accurate)
#pragma unroll
        for (int tt = 0; tt < 4; tt++) {
            int col = (w * 4 + tt) * 16 + m;
#pragma unroll
            for (int reg = 0; reg < 4; reg++) {
                int row = row0 + rbase + quad * 4 + reg;
                if (row < N) h1[(size_t)row * 256 + col] = f2bu(Cf[tt][reg]);
            }
        }
        if (w == 3 && m == 15) {
#pragma unroll
            for (int reg = 0; reg < 4; reg++) {
                int row = row0 + rbase + quad * 4 + reg;
                if (row < N) pk1[(size_t)row * 8 + 5] = Cf[3][reg];   // col 255
            }
        }
        // stats for head w
        float sl[4], sr[4];
#pragma unroll
        for (int reg = 0; reg < 4; reg++) {
            float a = 0.f, b = 0.f;
#pragma unroll
            for (int tt = 0; tt < 4; tt++) {
                a = fmaf(avl[tt], Cf[tt][reg], a);
                b = fmaf(avr[tt], Cf[tt][reg], b);
            }
            sl[reg] = a; sr[reg] = b;
        }
#pragma unroll
        for (int off = 8; off >= 1; off >>= 1) {
#pragma unroll
            for (int reg = 0; reg < 4; reg++) {
                sl[reg] += __shfl_down(sl[reg], off, 64);
                sr[reg] += __shfl_down(sr[reg], off, 64);
            }
        }
        if (m == 0) {
#pragma unroll
            for (int reg = 0; reg < 4; reg++) {
                int row = row0 + rbase + quad * 4 + reg;
                if (row < N) {
                    al1[(size_t)row * 4 + w] = sl[reg];
                    pk1[(size_t)row * 8 + w] = sr[reg];
                }
            }
        }
    }
    // reward weights: EXACT input col 127 from global (f32 when f32)
    if (t < 64) {
        int row = row0 + t;
        float rr = 0.f;
        if (row < N) {
            float a = fabsf(ldf(x, (size_t)row * 128 + 127, isbf));
            rr = 1.f / (a + 1e-6f);
            pk1[(size_t)row * 8 + 4] = logf(rr);
        }
        rpart[t] = rr;
    }
    __syncthreads();
    if (t == 0) {
        float s = 0.f;
#pragma unroll
        for (int i = 0; i < 64; i++) s += rpart[i];
        ATOMIC_ADD_F32(rwS, s);
    }
}

// ---------------- layer1 aggregation: max-free softmax, one dst/wave, padded CSR, depth-3 ----------------
// The proven-best agg1 schedule (R1/R3/R5 convergence at ~66us): one wave per dst node (fast
// block retirement -> CU refills), padded mask-free CSR, indices pre-resolved per 32-edge
// chunk (oldest in VMEM FIFO), depth-3 pipeline with 4 named buffers, regular stores (x2b
// must stay L2-resident for gemm2 -- NT store cost ~10us on the rest, R5 lesson).
__global__ __launch_bounds__(256) void k_agg1(const int* __restrict__ rowptr,
                                              const int* __restrict__ csr_src,
                                              const float* __restrict__ al1,
                                              const float* __restrict__ pk1,
                                              const float* __restrict__ rwS,
                                              const unsigned short* __restrict__ h1,
                                              unsigned short* __restrict__ x2b,
                                              float* __restrict__ x2c, int N) {
    const int d = blockIdx.x * 4 + (threadIdx.x >> 6);
    if (d >= N) return;
    const int lane = threadIdx.x & 63;
    const int q = lane & 15;          // column block
    const int g = lane >> 4;          // edge group
    const int h = q >> 2;             // head of this column block
    const bool last15 = (q == 15);
    const float gl = FGW * logf(fmaxf(*rwS, 1e-12f));
    const unsigned qo = (unsigned)q * 32u;
    const unsigned ho4 = (unsigned)h * 4u;
    const char* pk1c = (const char*)pk1;
    const char* h1c  = (const char*)h1;

    const float al_h = al1[(size_t)d * 4 + h];
    const int beg = rowptr[d], end = rowptr[d + 1];

    float acc[16];
#pragma unroll
    for (int k = 0; k < 16; k++) acc[k] = 0.f;
    float ssum = 0.f;

    for (int base = beg; base < end; base += 32) {
        const int nst = min(end - base, 32) >> 2;   // 1..8, exact (padded)

        int sj[8];
#pragma unroll
        for (int k = 0; k < 8; k++)
            if (k < nst) sj[k] = csr_src[base + k * 4 + g];

        float arP[4]; float2 lcP[4]; uint4 h0P[4], h1P[4];

#define LD1(K) do {                                                                   \
        int s_ = sj[(K)];                                                             \
        unsigned po_ = (unsigned)s_ * 32u;                                            \
        arP[(K) & 3] = *reinterpret_cast<const float*>(pk1c + po_ + ho4);             \
        lcP[(K) & 3] = *reinterpret_cast<const float2*>(pk1c + po_ + 16u);            \
        unsigned ho_ = (unsigned)s_ * 512u + qo;                                      \
        h0P[(K) & 3] = *reinterpret_cast<const uint4*>(h1c + ho_);                    \
        h1P[(K) & 3] = *reinterpret_cast<const uint4*>(h1c + ho_ + 16u);              \
    } while (0)

#define CONS1(K) do {                                                                 \
        float a_ = al_h + arP[(K) & 3];                                               \
        a_ = fmaxf(a_, NEG_SLOPE * a_);                                               \
        a_ = fmaf(FGW, lcP[(K) & 3].x, a_ - gl);                                      \
        float e_ = __expf(a_);                                                        \
        ssum += e_;                                                                   \
        uint4 cb0_ = h0P[(K) & 3], cb1_ = h1P[(K) & 3];                               \
        unsigned uu_; float lo_, hi_;                                                 \
        uu_ = cb0_.x; lo_ = __uint_as_float(uu_ << 16); hi_ = __uint_as_float(uu_ & 0xFFFF0000u); \
        acc[0] = fmaf(e_, lo_, acc[0]);  acc[1] = fmaf(e_, hi_, acc[1]);              \
        uu_ = cb0_.y; lo_ = __uint_as_float(uu_ << 16); hi_ = __uint_as_float(uu_ & 0xFFFF0000u); \
        acc[2] = fmaf(e_, lo_, acc[2]);  acc[3] = fmaf(e_, hi_, acc[3]);              \
        uu_ = cb0_.z; lo_ = __uint_as_float(uu_ << 16); hi_ = __uint_as_float(uu_ & 0xFFFF0000u); \
        acc[4] = fmaf(e_, lo_, acc[4]);  acc[5] = fmaf(e_, hi_, acc[5]);              \
        uu_ = cb0_.w; lo_ = __uint_as_float(uu_ << 16); hi_ = __uint_as_float(uu_ & 0xFFFF0000u); \
        acc[6] = fmaf(e_, lo_, acc[6]);  acc[7] = fmaf(e_, hi_, acc[7]);              \
        uu_ = cb1_.x; lo_ = __uint_as_float(uu_ << 16); hi_ = __uint_as_float(uu_ & 0xFFFF0000u); \
        acc[8] = fmaf(e_, lo_, acc[8]);  acc[9] = fmaf(e_, hi_, acc[9]);              \
        uu_ = cb1_.y; lo_ = __uint_as_float(uu_ << 16); hi_ = __uint_as_float(uu_ & 0xFFFF0000u); \
        acc[10] = fmaf(e_, lo_, acc[10]); acc[11] = fmaf(e_, hi_, acc[11]);           \
        uu_ = cb1_.z; lo_ = __uint_as_float(uu_ << 16); hi_ = __uint_as_float(uu_ & 0xFFFF0000u); \
        acc[12] = fmaf(e_, lo_, acc[12]); acc[13] = fmaf(e_, hi_, acc[13]);           \
        uu_ = cb1_.w; lo_ = __uint_as_float(uu_ << 16); hi_ = __uint_as_float(uu_ & 0xFFFF0000u); \
        hi_ = last15 ? lcP[(K) & 3].y : hi_;   /* exact fp32 for log-sensitive col 255 */ \
        acc[14] = fmaf(e_, lo_, acc[14]); acc[15] = fmaf(e_, hi_, acc[15]);           \
    } while (0)

        LD1(0);
        if (1 < nst) LD1(1);
        if (2 < nst) LD1(2);
#pragma unroll
        for (int k = 0; k < 8; k++) {
            if (k >= nst) break;
            if (k + 3 < 8) { if (k + 3 < nst) LD1(k + 3); }
            CONS1(k);
        }
#undef LD1
#undef CONS1
    }

    // merge the 4 edge-group partials (lanes with equal q)
#pragma unroll
    for (int k = 0; k < 16; k++) {
        acc[k] += __shfl_xor(acc[k], 16, 64);
        acc[k] += __shfl_xor(acc[k], 32, 64);
    }
    ssum += __shfl_xor(ssum, 16, 64);
    ssum += __shfl_xor(ssum, 32, 64);

    const float inv = 1.f / (ssum + 1e-16f);
    // lane (g,q) finalizes cols q*16 + g*4 .. +3  (constant-indexed selects; no scratch)
    float o0 = (g == 0 ? acc[0] : g == 1 ? acc[4]  : g == 2 ? acc[8]  : acc[12]);
    float o1 = (g == 0 ? acc[1] : g == 1 ? acc[5]  : g == 2 ? acc[9]  : acc[13]);
    float o2 = (g == 0 ? acc[2] : g == 1 ? acc[6]  : g == 2 ? acc[10] : acc[14]);
    float o3 = (g == 0 ? acc[3] : g == 1 ? acc[7]  : g == 2 ? acc[11] : acc[15]);
    o0 *= inv; o1 *= inv; o2 *= inv; o3 *= inv;
    o0 = (o0 > 0.f) ? o0 : expm1f(o0);
    o1 = (o1 > 0.f) ? o1 : expm1f(o1);
    o2 = (o2 > 0.f) ? o2 : expm1f(o2);
    o3 = (o3 > 0.f) ? o3 : expm1f(o3);
    uint2 ob;
    ob.x = (unsigned)f2bu(o0) | ((unsigned)f2bu(o1) << 16);
    ob.y = (unsigned)f2bu(o2) | ((unsigned)f2bu(o3) << 16);
    *reinterpret_cast<uint2*>(&x2b[(size_t)d * 256 + q * 16 + g * 4]) = ob;
    if (lane == 63) x2c[d] = o3;   // fp32 post-ELU col 255
}

// ---------------- GEMM2 (64 rows/block, MFMA): h2(bf16) = x2@W2 ; stats ; rwsum2 ----------------
// Block 0 also initializes the layer-2 fake src row N (h2[N]=0, pk2[N]={-1e30, 0}).
__global__ __launch_bounds__(256) void k_gemm2f(const unsigned short* __restrict__ x2b,
                                                const float* __restrict__ x2c,
                                                const unsigned short* __restrict__ Wp2,
                                                const void* __restrict__ attl,
                                                const void* __restrict__ attr,
                                                unsigned short* __restrict__ h2,
                                                float* __restrict__ pk2,     // [N+1][2]
                                                float* __restrict__ al2,
                                                float* __restrict__ rwS2,
                                                int N, const int* __restrict__ flag) {
    const int isbf = *flag;
    __shared__ unsigned short As[64 * 264];   // 33.8 KB
    __shared__ float pl[4 * 64], pr[4 * 64], rpart[64];
    const int row0 = blockIdx.x * 64;
    const int t = threadIdx.x;
    const int w = t >> 6, lane = t & 63;
    const int m = lane & 15, quad = lane >> 4;

    if (blockIdx.x == 0) {   // fake row N init (h1 region is dead now; h2 overlays it)
        if (t < 8) *reinterpret_cast<uint4*>(&h2[(size_t)N * 64 + t * 8]) = (uint4){0u, 0u, 0u, 0u};
        if (t == 0) { pk2[(size_t)N * 2] = -1e30f; pk2[(size_t)N * 2 + 1] = 0.f; }
    }

#pragma unroll
    for (int it = 0; it < 8; it++) {
        int idx = it * 256 + t;          // [0,2048)
        int r = idx >> 5, c = idx & 31;
        uint4 v = {0u, 0u, 0u, 0u};
        if (row0 + r < N)
            v = *reinterpret_cast<const uint4*>(x2b + (size_t)(row0 + r) * 256 + c * 8);
        *reinterpret_cast<uint4*>(&As[r * 264 + c * 8]) = v;
    }
    __syncthreads();
    // wave's 8 B-frags (col-tile w), reused across 4 row-subtiles
    bf16x8 Bf[8];
#pragma unroll
    for (int ko = 0; ko < 8; ko++)
        Bf[ko] = *reinterpret_cast<const bf16x8*>(&Wp2[(size_t)((w * 8 + ko) * 64 + lane) * 8]);
    f32x4 Cf[4];
#pragma unroll
    for (int sub = 0; sub < 4; sub++) Cf[sub] = (f32x4){0.f, 0.f, 0.f, 0.f};
#pragma unroll
    for (int ko = 0; ko < 8; ko++)
#pragma unroll
        for (int sub = 0; sub < 4; sub++) {   // 4 independent chains per ko step
            bf16x8 Af = *reinterpret_cast<const bf16x8*>(
                &As[(sub * 16 + m) * 264 + ko * 32 + quad * 8]);
            Cf[sub] = __builtin_amdgcn_mfma_f32_16x16x32_bf16(Af, Bf[ko], Cf[sub], 0, 0, 0);
        }
    int col = w * 16 + m;
    float avl = ldf(attl, col, isbf);
    float avr = ldf(attr, col, isbf);
#pragma unroll
    for (int sub = 0; sub < 4; sub++) {
#pragma unroll
        for (int reg = 0; reg < 4; reg++) {
            int row = row0 + sub * 16 + quad * 4 + reg;
            if (row < N) h2[(size_t)row * 64 + col] = f2bu(Cf[sub][reg]);
        }
        float sl[4], sr[4];
#pragma unroll
        for (int reg = 0; reg < 4; reg++) { sl[reg] = avl * Cf[sub][reg]; sr[reg] = avr * Cf[sub][reg]; }
#pragma unroll
        for (int off = 8; off >= 1; off >>= 1) {
#pragma unroll
            for (int reg = 0; reg < 4; reg++) {
                sl[reg] += __shfl_down(sl[reg], off, 64);
                sr[reg] += __shfl_down(sr[reg], off, 64);
            }
        }
        if (m == 0) {
#pragma unroll
            for (int reg = 0; reg < 4; reg++) {
                pl[sub * 64 + w * 16 + quad * 4 + reg] = sl[reg];
                pr[sub * 64 + w * 16 + quad * 4 + reg] = sr[reg];
            }
        }
    }
    __syncthreads();
    if (t < 64) {
        int row = row0 + t;
        int sub = t >> 4, ri = t & 15;
        float rr = 0.f;
        if (row < N) {
            al2[row] = pl[sub * 64 + ri] + pl[sub * 64 + 16 + ri] + pl[sub * 64 + 32 + ri] + pl[sub * 64 + 48 + ri];
            pk2[(size_t)row * 2] = pr[sub * 64 + ri] + pr[sub * 64 + 16 + ri] + pr[sub * 64 + 32 + ri] + pr[sub * 64 + 48 + ri];
            float a = fabsf(x2c[row]);   // fp32 sidecar: exact post-ELU col 255
            rr = 1.f / (a + 1e-6f);
            pk2[(size_t)row * 2 + 1] = logf(rr);
        }
        rpart[t] = rr;
    }
    __syncthreads();
    if (t == 0) {
        float s = 0.f;
#pragma unroll
        for (int i = 0; i < 64; i++) s += rpart[i];
        ATOMIC_ADD_F32(rwS2, s);
    }
}

// ---------------- layer2 aggregation + ELU + FC -> y (PERSISTENT grid, padded CSR, depth-3) ----------------
// R4's agg2 variant: persistent 2048-block grid-stride. Light per-dst state (4 acc + ssum) makes
// the d-loop serialization cheap, and the rest-of-pipeline measured ~10-14us faster with it (R4).
__global__ __launch_bounds__(256) void k_agg2(const int* __restrict__ rowptr,
                                              const int* __restrict__ csr_src,
                                              const float* __restrict__ al2,
                                              const float* __restrict__ pk2,
                                              const float* __restrict__ rwS2,
                                              const unsigned short* __restrict__ h2,
                                              const void* __restrict__ fcw,
                                              const void* __restrict__ fcb,
                                              void* __restrict__ y, int N,
                                              const int* __restrict__ flag) {
    const int isbf = *flag;
    const int lane = threadIdx.x & 63;
    const int wid = threadIdx.x >> 6;
    const int q = lane & 15;
    const int g = lane >> 4;
    const float gl2 = FGW * logf(fmaxf(*rwS2, 1e-12f));
    const char* pk2c = (const char*)pk2;
    const char* h2c  = (const char*)h2;
    const unsigned qo8 = (unsigned)q * 8u;
    const int stride = gridDim.x * 4;
    const float fw = ldf(fcw, q * 4 + g, isbf);
    const float fb = ldf(fcb, 0, isbf);

    for (int d = blockIdx.x * 4 + wid; d < N; d += stride) {
        const float al_d = al2[d];
        const int beg = rowptr[d], end = rowptr[d + 1];

        float acc[4];
#pragma unroll
        for (int k = 0; k < 4; k++) acc[k] = 0.f;
        float ssum = 0.f;

        for (int base = beg; base < end; base += 32) {
            const int nst = min(end - base, 32) >> 2;

            int sj[8];
#pragma unroll
            for (int k = 0; k < 8; k++)
                if (k < nst) sj[k] = csr_src[base + k * 4 + g];

            float2 pvP[4]; uint2 hbP[4];

#define LD2(K) do {                                                                    \
        int s_ = sj[(K)];                                                              \
        pvP[(K) & 3] = *reinterpret_cast<const float2*>(pk2c + (unsigned)s_ * 8u);     \
        hbP[(K) & 3] = *reinterpret_cast<const uint2*>(h2c + (unsigned)s_ * 128u + qo8); \
    } while (0)

#define CONS2(K) do {                                                                  \
        float a_ = al_d + pvP[(K) & 3].x;                                              \
        a_ = fmaxf(a_, NEG_SLOPE * a_);                                                \
        a_ = fmaf(FGW, pvP[(K) & 3].y, a_ - gl2);                                      \
        float e_ = __expf(a_);                                                         \
        ssum += e_;                                                                    \
        unsigned uu_ = hbP[(K) & 3].x;                                                 \
        acc[0] = fmaf(e_, __uint_as_float(uu_ << 16), acc[0]);                         \
        acc[1] = fmaf(e_, __uint_as_float(uu_ & 0xFFFF0000u), acc[1]);                 \
        uu_ = hbP[(K) & 3].y;                                                          \
        acc[2] = fmaf(e_, __uint_as_float(uu_ << 16), acc[2]);                         \
        acc[3] = fmaf(e_, __uint_as_float(uu_ & 0xFFFF0000u), acc[3]);                 \
    } while (0)

            LD2(0);
            if (1 < nst) LD2(1);
            if (2 < nst) LD2(2);
#pragma unroll
            for (int k = 0; k < 8; k++) {
                if (k >= nst) break;
                if (k + 3 < 8) { if (k + 3 < nst) LD2(k + 3); }
                CONS2(k);
            }
#undef LD2
#undef CONS2
        }

#pragma unroll
        for (int k = 0; k < 4; k++) {
            acc[k] += __shfl_xor(acc[k], 16, 64);
            acc[k] += __shfl_xor(acc[k], 32, 64);
        }
        ssum += __shfl_xor(ssum, 16, 64);
        ssum += __shfl_xor(ssum, 32, 64);

        // lane (g,q) owns col q*4+g (bijective over 64 lanes)
        float v = (g == 0 ? acc[0] : g == 1 ? acc[1] : g == 2 ? acc[2] : acc[3]) / (ssum + 1e-16f);
        v = (v > 0.f) ? v : expm1f(v);
        float r = waveReduceSum(v * fw);
        if (lane == 0) {
            float o = r + fb;
            if (isbf) ((bf16*)y)[d] = __float2bfloat16(o);
            else      ((float*)y)[d] = o;
        }
    }
}

extern "C" void kernel_launch(void* const* d_in, const int* in_sizes, int n_in,
                              void* d_out, int out_size, void* d_ws, size_t ws_size,
                              hipStream_t stream) {
    const void* x     = d_in[0];
    const int*  ei    = (const int*)d_in[1];
    const void* W1    = d_in[2];
    const void* attl1 = d_in[3];
    const void* attr1 = d_in[4];
    const void* W2    = d_in[5];
    const void* attl2 = d_in[6];
    const void* attr2 = d_in[7];
    const void* fcw   = d_in[8];
    const void* fcb   = d_in[9];

    const int N = in_sizes[0] / 128;  // 50000
    const int E = in_sizes[1] / 2;    // 800000
    const int NB = (N + 255) / 256;   // scan chunks
    const int E2 = E + 4 * N;         // padded CSR capacity

    // ---- workspace layout (~62 MB) ----
    float* p = (float*)d_ws;
    unsigned short* h1 = (unsigned short*)p; p += (size_t)(N + 1) * 128;   // (N+1)*256 bf16 (+fake row)
    float* pk1    = p; p += (size_t)(N + 1) * 8;   // {ar[4], logr, h1c255, pad, pad} (+fake row)
    float* al1    = p; p += (size_t)N * 4;
    unsigned short* x2b = (unsigned short*)p; p += (size_t)N * 128;  // N*256 bf16
    float* x2c    = p; p += (size_t)N;       // fp32 post-ELU col 255
    float* pk2    = p; p += (size_t)(N + 1) * 2;   // {ar2, logr2} (+fake row)
    float* al2    = p; p += (size_t)N;
    int* rowptr   = (int*)p; p += (size_t)N + 1;
    int* deg      = (int*)p; p += (size_t)N;
    int* cursor   = (int*)p; p += (size_t)N;
    int* stmp     = (int*)p; p += (size_t)N;   // scan phase-A inclusive partials
    int* bsum     = (int*)p; p += (size_t)NB;  // scan block sums
    int* csr_src  = (int*)p; p += (size_t)E2;  // padded CSR
    p = (float*)(((uintptr_t)p + 15) & ~(uintptr_t)15);  // 16B align for frag loads
    unsigned short* Wp1h = (unsigned short*)p; p += 16384;  // 32768 bf16
    unsigned short* Wp1l = (unsigned short*)p; p += 16384;  // 32768 bf16
    unsigned short* Wp2  = (unsigned short*)p; p += 8192;   // 16384 bf16
    float* sscal  = p; p += 4;               // [0]=rwsum L1, [1]=rwsum L2, [2]=dtype flag
    int* dflag = (int*)(sscal + 2);

    unsigned short* h2 = h1;   // layer2 bf16 h2 ((N+1)*64) overlays h1 region (dead after agg1)

    // deg must be zero before the histogram (ws re-poisoned each call)
    hipMemsetAsync(deg, 0, (size_t)N * 4, stream);

    // ---- CSR build + dtype detect + weight packing ----
    k_degdet<<<(E + 255) / 256, 256, 0, stream>>>(ei, deg, E, (const unsigned short*)x, sscal, dflag,
                                                  W1, W2, Wp1h, Wp1l, Wp2);
    k_scanA<<<NB, 256, 0, stream>>>(deg, stmp, bsum, N);
    k_scanB<<<1, 256, 0, stream>>>(bsum, NB, &rowptr[N]);
    k_scanC<<<NB, 256, 0, stream>>>(deg, stmp, bsum, rowptr, cursor, csr_src, N);
    k_scatter<<<(E + 255) / 256, 256, 0, stream>>>(ei, rowptr, cursor, csr_src, E);

    // ---- layer 1 ----
    k_gemm1f<<<(N + 63) / 64, 256, 0, stream>>>(x, Wp1h, Wp1l, attl1, attr1, h1, pk1, al1,
                                                &sscal[0], N, dflag);
    k_agg1<<<(N + 3) / 4, 256, 0, stream>>>(rowptr, csr_src, al1, pk1,
                                            &sscal[0], h1, x2b, x2c, N);

    // ---- layer 2 ----
    k_gemm2f<<<(N + 63) / 64, 256, 0, stream>>>(x2b, x2c, Wp2, attl2, attr2, h2, pk2, al2,
                                                &sscal[1], N, dflag);
    const int ag2 = min((N + 3) / 4, 2048);   // persistent: 8 blocks/CU (R4's rest advantage)
    k_agg2<<<ag2, 256, 0, stream>>>(rowptr, csr_src, al2, pk2,
                                    &sscal[1], h2, fcw, fcb, d_out, N, dflag);
}